// Round 3
// baseline (167.410 us; speedup 1.0000x reference)
//
#include <hip/hip_runtime.h>

// SE(3) exp + point transform — round-1 register structure + NONTEMPORAL
// stores. Rounds 0-2 (three structurally different kernels) all saturate at
// 2.4 TB/s summed HBM while fillBuffer hits 6.4 TB/s on the same pages; MLP
// arithmetic rules out latency-boundedness. Theory: write-allocate of the
// never-re-read output stream into L2/L3 (a) evicts the input (only 50% L3
// read-hit: FETCH=43MB of an 84MB input) and (b) adds cache-management
// overhead per line. Fix under test: stream stores past the caches with the
// nt bit; keep loads cached so input L3 hits grow.

typedef float f4 __attribute__((ext_vector_type(4)));

__device__ __forceinline__ float rfl(float x) {
    // block-uniform value -> SGPR (all lanes hold identical values)
    return __uint_as_float(__builtin_amdgcn_readfirstlane(__float_as_uint(x)));
}

__global__ __launch_bounds__(256) void se3_apply_kernel(
    const float* __restrict__ X,      // (BT, N, 3) flattened
    const float* __restrict__ dofs,   // (BT, 6)
    float* __restrict__ out,
    int n3,                            // floats per (b,t) = N*3
    int tilesPerBT)
{
    const int bt   = blockIdx.x / tilesPerBT;
    const int tile = blockIdx.x - bt * tilesPerBT;
    const int t    = threadIdx.x;

    const int fInBT = tile * 3072 + t * 12;                 // float offset within bt
    const long long baseF = (long long)bt * (long long)n3 + (long long)fInBT;
    const f4* __restrict__ Xp = (const f4*)(X + baseF);
    f4* __restrict__ Op       = (f4*)(out + baseF);

    // ---- issue the 3 independent loads first (overlap with SE3 setup) ----
    const bool full = (fInBT + 12) <= n3;
    f4 v0, v1, v2;
    if (full) { v0 = Xp[0]; v1 = Xp[1]; v2 = Xp[2]; }

    // ---- SE(3) exponential (block-uniform) ----
    const float* d = dofs + bt * 6;
    const float tx = d[0], ty = d[1], tz = d[2];
    const float wx = d[3], wy = d[4], wz = d[5];

    const float nrm2  = wx * wx + wy * wy + wz * wz;
    const float th2   = fmaxf(nrm2, 1e-4f);      // jnp.clip(nrms, 1e-4) (min only)
    const float theta = sqrtf(th2);
    const float st = sinf(theta);
    const float ct = cosf(theta);
    const float f1 = st / theta;
    const float f2 = (1.0f - ct) / th2;
    const float f3 = (theta - st) / (th2 * theta);

    const float xx = wx * wx, yy = wy * wy, zz = wz * wz;
    const float xy = wx * wy, xz = wx * wz, yz = wy * wz;

    const float R00 = rfl(1.0f - f2 * (yy + zz));
    const float R01 = rfl(f2 * xy - f1 * wz);
    const float R02 = rfl(f2 * xz + f1 * wy);
    const float R10 = rfl(f2 * xy + f1 * wz);
    const float R11 = rfl(1.0f - f2 * (xx + zz));
    const float R12 = rfl(f2 * yz - f1 * wx);
    const float R20 = rfl(f2 * xz - f1 * wy);
    const float R21 = rfl(f2 * yz + f1 * wx);
    const float R22 = rfl(1.0f - f2 * (xx + yy));

    const float V00 = 1.0f - f3 * (yy + zz);
    const float V01 = f3 * xy - f2 * wz;
    const float V02 = f3 * xz + f2 * wy;
    const float V10 = f3 * xy + f2 * wz;
    const float V11 = 1.0f - f3 * (xx + zz);
    const float V12 = f3 * yz - f2 * wx;
    const float V20 = f3 * xz - f2 * wy;
    const float V21 = f3 * yz + f2 * wx;
    const float V22 = 1.0f - f3 * (xx + yy);

    const float Tx = rfl(V00 * tx + V01 * ty + V02 * tz);
    const float Ty = rfl(V10 * tx + V11 * ty + V12 * tz);
    const float Tz = rfl(V20 * tx + V21 * ty + V22 * tz);

    if (full) {
        // 4 points unpacked from 3 float4s
        const float x0 = v0.x, y0 = v0.y, z0 = v0.z;
        const float x1 = v0.w, y1 = v1.x, z1 = v1.y;
        const float x2 = v1.z, y2 = v1.w, z2 = v2.x;
        const float x3 = v2.y, y3 = v2.z, z3 = v2.w;

        f4 o0, o1, o2;
        o0.x = fmaf(R00, x0, fmaf(R01, y0, fmaf(R02, z0, Tx)));
        o0.y = fmaf(R10, x0, fmaf(R11, y0, fmaf(R12, z0, Ty)));
        o0.z = fmaf(R20, x0, fmaf(R21, y0, fmaf(R22, z0, Tz)));
        o0.w = fmaf(R00, x1, fmaf(R01, y1, fmaf(R02, z1, Tx)));
        o1.x = fmaf(R10, x1, fmaf(R11, y1, fmaf(R12, z1, Ty)));
        o1.y = fmaf(R20, x1, fmaf(R21, y1, fmaf(R22, z1, Tz)));
        o1.z = fmaf(R00, x2, fmaf(R01, y2, fmaf(R02, z2, Tx)));
        o1.w = fmaf(R10, x2, fmaf(R11, y2, fmaf(R12, z2, Ty)));
        o2.x = fmaf(R20, x2, fmaf(R21, y2, fmaf(R22, z2, Tz)));
        o2.y = fmaf(R00, x3, fmaf(R01, y3, fmaf(R02, z3, Tx)));
        o2.z = fmaf(R10, x3, fmaf(R11, y3, fmaf(R12, z3, Ty)));
        o2.w = fmaf(R20, x3, fmaf(R21, y3, fmaf(R22, z3, Tz)));

        // nontemporal: stream the never-re-read output past L2/L3
        __builtin_nontemporal_store(o0, Op + 0);
        __builtin_nontemporal_store(o1, Op + 1);
        __builtin_nontemporal_store(o2, Op + 2);
    } else {
        // generic tail: whole points only (n3 is always a multiple of 3)
        const long long base = (long long)bt * (long long)n3;
        for (int f = fInBT; f + 3 <= n3; f += 3) {
            const float px = X[base + f + 0], py = X[base + f + 1], pz = X[base + f + 2];
            out[base + f + 0] = fmaf(R00, px, fmaf(R01, py, fmaf(R02, pz, Tx)));
            out[base + f + 1] = fmaf(R10, px, fmaf(R11, py, fmaf(R12, pz, Ty)));
            out[base + f + 2] = fmaf(R20, px, fmaf(R21, py, fmaf(R22, pz, Tz)));
        }
    }
}

extern "C" void kernel_launch(void* const* d_in, const int* in_sizes, int n_in,
                              void* d_out, int out_size, void* d_ws, size_t ws_size,
                              hipStream_t stream) {
    const float* X    = (const float*)d_in[0];
    const float* dofs = (const float*)d_in[1];
    float* out        = (float*)d_out;

    const int BT = in_sizes[1] / 6;            // 64*28 = 1792
    const int n3 = in_sizes[0] / BT;           // 4096*3 = 12288 floats per bt

    const int tilesPerBT = (n3 + 3071) / 3072; // 4 for N=4096

    dim3 grid((unsigned)(BT * tilesPerBT));    // 7168 blocks
    se3_apply_kernel<<<grid, 256, 0, stream>>>(X, dofs, out, n3, tilesPerBT);
}

// Round 4
// 167.003 us; speedup vs baseline: 1.0024x; 1.0024x over previous
//
#include <hip/hip_runtime.h>

// SE(3) exp + point transform — two-kernel split: tiny pre-kernel computes
// R|T per (b,t) into d_ws; hot kernel is a copy-shaped pure stream.
//
// Evidence so far: R0 (LDS coalesced), R1 (48B-stride regs), R2 (persistent
// prefetch, SE3 amortized), R3 (nt stores) ALL converge at 2.4-2.6 TB/s
// summed HBM, while fillBuffer does 6.4 and m13's float4 copy (same 1:1 R/W
// mix) does 6.3. Remaining untested lever: per-wave read duty-cycle and
// in-flight depth. Here each hot wave issues 6 float4 loads (96 B/thread,
// 2x R1) as its first instructions, R|T arrives via the scalar path
// (uniform address -> s_load, no vmcnt), then 72 FMAs + 6 stores and exit.
// No transcendentals, no barriers, no LDS in the hot kernel.

typedef float f4 __attribute__((ext_vector_type(4)));

// ---------------- kernel A: 1792x SE(3) exp -> ws (16 floats per bt) -------
__global__ __launch_bounds__(256) void se3_pre(
    const float* __restrict__ dofs, float* __restrict__ ws, int BT)
{
    const int i = blockIdx.x * 256 + threadIdx.x;
    if (i >= BT) return;
    const float* d = dofs + i * 6;
    const float tx = d[0], ty = d[1], tz = d[2];
    const float wx = d[3], wy = d[4], wz = d[5];

    const float nrm2  = wx * wx + wy * wy + wz * wz;
    const float th2   = fmaxf(nrm2, 1e-4f);      // jnp.clip(nrms, 1e-4)
    const float theta = sqrtf(th2);
    const float st = sinf(theta);
    const float ct = cosf(theta);
    const float f1 = st / theta;
    const float f2 = (1.0f - ct) / th2;
    const float f3 = (theta - st) / (th2 * theta);

    const float xx = wx * wx, yy = wy * wy, zz = wz * wz;
    const float xy = wx * wy, xz = wx * wz, yz = wy * wz;

    const float R00 = 1.0f - f2 * (yy + zz);
    const float R01 = f2 * xy - f1 * wz;
    const float R02 = f2 * xz + f1 * wy;
    const float R10 = f2 * xy + f1 * wz;
    const float R11 = 1.0f - f2 * (xx + zz);
    const float R12 = f2 * yz - f1 * wx;
    const float R20 = f2 * xz - f1 * wy;
    const float R21 = f2 * yz + f1 * wx;
    const float R22 = 1.0f - f2 * (xx + yy);

    const float V00 = 1.0f - f3 * (yy + zz);
    const float V01 = f3 * xy - f2 * wz;
    const float V02 = f3 * xz + f2 * wy;
    const float V10 = f3 * xy + f2 * wz;
    const float V11 = 1.0f - f3 * (xx + zz);
    const float V12 = f3 * yz - f2 * wx;
    const float V20 = f3 * xz - f2 * wy;
    const float V21 = f3 * yz + f2 * wx;
    const float V22 = 1.0f - f3 * (xx + yy);

    const float Tx = V00 * tx + V01 * ty + V02 * tz;
    const float Ty = V10 * tx + V11 * ty + V12 * tz;
    const float Tz = V20 * tx + V21 * ty + V22 * tz;

    f4* W = (f4*)(ws + (long long)i * 16);
    W[0] = (f4){R00, R01, R02, Tx};
    W[1] = (f4){R10, R11, R12, Ty};
    W[2] = (f4){R20, R21, R22, Tz};
}

// ---------------- kernel B: copy-shaped streaming transform ----------------
// tile = 6144 floats (2048 points, 24 KB); thread owns 8 points = 6 float4.
__global__ __launch_bounds__(256) void se3_stream(
    const float* __restrict__ X, const float* __restrict__ ws,
    float* __restrict__ out, int n3, int tilesPerBT)
{
    const int bt   = blockIdx.x / tilesPerBT;
    const int tile = blockIdx.x - bt * tilesPerBT;
    const int t    = threadIdx.x;

    const int fInBT = tile * 6144 + t * 24;
    const long long baseF = (long long)bt * (long long)n3 + (long long)fInBT;
    const f4* __restrict__ Xp = (const f4*)(X + baseF);
    f4* __restrict__ Op       = (f4*)(out + baseF);

    // ---- first instructions of the wave: put 96 B/lane of reads in flight ----
    const bool full = (fInBT + 24) <= n3;
    f4 v0, v1, v2, v3, v4, v5;
    if (full) {
        v0 = Xp[0]; v1 = Xp[1]; v2 = Xp[2];
        v3 = Xp[3]; v4 = Xp[4]; v5 = Xp[5];
    }

    // ---- R|T via uniform address (scalar cache path, no vmcnt) ----
    const f4* __restrict__ W = (const f4*)(ws + (long long)bt * 16);
    const f4 w0 = W[0], w1 = W[1], w2 = W[2];

    if (full) {
        const float s[24] = {v0.x, v0.y, v0.z, v0.w, v1.x, v1.y, v1.z, v1.w,
                             v2.x, v2.y, v2.z, v2.w, v3.x, v3.y, v3.z, v3.w,
                             v4.x, v4.y, v4.z, v4.w, v5.x, v5.y, v5.z, v5.w};
        float r[24];
#pragma unroll
        for (int k = 0; k < 8; ++k) {
            const float x = s[3 * k], y = s[3 * k + 1], z = s[3 * k + 2];
            r[3 * k]     = fmaf(w0.x, x, fmaf(w0.y, y, fmaf(w0.z, z, w0.w)));
            r[3 * k + 1] = fmaf(w1.x, x, fmaf(w1.y, y, fmaf(w1.z, z, w1.w)));
            r[3 * k + 2] = fmaf(w2.x, x, fmaf(w2.y, y, fmaf(w2.z, z, w2.w)));
        }
        Op[0] = (f4){r[0],  r[1],  r[2],  r[3]};
        Op[1] = (f4){r[4],  r[5],  r[6],  r[7]};
        Op[2] = (f4){r[8],  r[9],  r[10], r[11]};
        Op[3] = (f4){r[12], r[13], r[14], r[15]};
        Op[4] = (f4){r[16], r[17], r[18], r[19]};
        Op[5] = (f4){r[20], r[21], r[22], r[23]};
    } else {
        // tail: whole points within this thread's 24-float slot (24 % 3 == 0,
        // so points never straddle slots)
        const long long base = (long long)bt * (long long)n3;
        for (int f = fInBT; f + 3 <= n3 && f < fInBT + 24; f += 3) {
            const float px = X[base + f + 0], py = X[base + f + 1], pz = X[base + f + 2];
            out[base + f + 0] = fmaf(w0.x, px, fmaf(w0.y, py, fmaf(w0.z, pz, w0.w)));
            out[base + f + 1] = fmaf(w1.x, px, fmaf(w1.y, py, fmaf(w1.z, pz, w1.w)));
            out[base + f + 2] = fmaf(w2.x, px, fmaf(w2.y, py, fmaf(w2.z, pz, w2.w)));
        }
    }
}

// ---------------- fallback (R1 structure) if workspace too small -----------
__device__ __forceinline__ float rfl(float x) {
    return __uint_as_float(__builtin_amdgcn_readfirstlane(__float_as_uint(x)));
}

__global__ __launch_bounds__(256) void se3_apply_fused(
    const float* __restrict__ X, const float* __restrict__ dofs,
    float* __restrict__ out, int n3, int tilesPerBT)
{
    const int bt   = blockIdx.x / tilesPerBT;
    const int tile = blockIdx.x - bt * tilesPerBT;
    const int t    = threadIdx.x;
    const int fInBT = tile * 3072 + t * 12;
    const long long baseF = (long long)bt * (long long)n3 + (long long)fInBT;
    const f4* __restrict__ Xp = (const f4*)(X + baseF);
    f4* __restrict__ Op       = (f4*)(out + baseF);

    const bool full = (fInBT + 12) <= n3;
    f4 v0, v1, v2;
    if (full) { v0 = Xp[0]; v1 = Xp[1]; v2 = Xp[2]; }

    const float* d = dofs + bt * 6;
    const float tx = d[0], ty = d[1], tz = d[2];
    const float wx = d[3], wy = d[4], wz = d[5];
    const float nrm2  = wx * wx + wy * wy + wz * wz;
    const float th2   = fmaxf(nrm2, 1e-4f);
    const float theta = sqrtf(th2);
    const float st = sinf(theta), ct = cosf(theta);
    const float f1 = st / theta;
    const float f2 = (1.0f - ct) / th2;
    const float f3 = (theta - st) / (th2 * theta);
    const float xx = wx * wx, yy = wy * wy, zz = wz * wz;
    const float xy = wx * wy, xz = wx * wz, yz = wy * wz;
    const float R00 = rfl(1.0f - f2 * (yy + zz));
    const float R01 = rfl(f2 * xy - f1 * wz);
    const float R02 = rfl(f2 * xz + f1 * wy);
    const float R10 = rfl(f2 * xy + f1 * wz);
    const float R11 = rfl(1.0f - f2 * (xx + zz));
    const float R12 = rfl(f2 * yz - f1 * wx);
    const float R20 = rfl(f2 * xz - f1 * wy);
    const float R21 = rfl(f2 * yz + f1 * wx);
    const float R22 = rfl(1.0f - f2 * (xx + yy));
    const float V00 = 1.0f - f3 * (yy + zz);
    const float V01 = f3 * xy - f2 * wz;
    const float V02 = f3 * xz + f2 * wy;
    const float V10 = f3 * xy + f2 * wz;
    const float V11 = 1.0f - f3 * (xx + zz);
    const float V12 = f3 * yz - f2 * wx;
    const float V20 = f3 * xz - f2 * wy;
    const float V21 = f3 * yz + f2 * wx;
    const float V22 = 1.0f - f3 * (xx + yy);
    const float Tx = rfl(V00 * tx + V01 * ty + V02 * tz);
    const float Ty = rfl(V10 * tx + V11 * ty + V12 * tz);
    const float Tz = rfl(V20 * tx + V21 * ty + V22 * tz);

    if (full) {
        const float x0 = v0.x, y0 = v0.y, z0 = v0.z;
        const float x1 = v0.w, y1 = v1.x, z1 = v1.y;
        const float x2 = v1.z, y2 = v1.w, z2 = v2.x;
        const float x3 = v2.y, y3 = v2.z, z3 = v2.w;
        f4 o0, o1, o2;
        o0.x = fmaf(R00, x0, fmaf(R01, y0, fmaf(R02, z0, Tx)));
        o0.y = fmaf(R10, x0, fmaf(R11, y0, fmaf(R12, z0, Ty)));
        o0.z = fmaf(R20, x0, fmaf(R21, y0, fmaf(R22, z0, Tz)));
        o0.w = fmaf(R00, x1, fmaf(R01, y1, fmaf(R02, z1, Tx)));
        o1.x = fmaf(R10, x1, fmaf(R11, y1, fmaf(R12, z1, Ty)));
        o1.y = fmaf(R20, x1, fmaf(R21, y1, fmaf(R22, z1, Tz)));
        o1.z = fmaf(R00, x2, fmaf(R01, y2, fmaf(R02, z2, Tx)));
        o1.w = fmaf(R10, x2, fmaf(R11, y2, fmaf(R12, z2, Ty)));
        o2.x = fmaf(R20, x2, fmaf(R21, y2, fmaf(R22, z2, Tz)));
        o2.y = fmaf(R00, x3, fmaf(R01, y3, fmaf(R02, z3, Tx)));
        o2.z = fmaf(R10, x3, fmaf(R11, y3, fmaf(R12, z3, Ty)));
        o2.w = fmaf(R20, x3, fmaf(R21, y3, fmaf(R22, z3, Tz)));
        Op[0] = o0; Op[1] = o1; Op[2] = o2;
    } else {
        const long long base = (long long)bt * (long long)n3;
        for (int f = fInBT; f + 3 <= n3 && f < fInBT + 12; f += 3) {
            const float px = X[base + f + 0], py = X[base + f + 1], pz = X[base + f + 2];
            out[base + f + 0] = fmaf(R00, px, fmaf(R01, py, fmaf(R02, pz, Tx)));
            out[base + f + 1] = fmaf(R10, px, fmaf(R11, py, fmaf(R12, pz, Ty)));
            out[base + f + 2] = fmaf(R20, px, fmaf(R21, py, fmaf(R22, pz, Tz)));
        }
    }
}

extern "C" void kernel_launch(void* const* d_in, const int* in_sizes, int n_in,
                              void* d_out, int out_size, void* d_ws, size_t ws_size,
                              hipStream_t stream) {
    const float* X    = (const float*)d_in[0];
    const float* dofs = (const float*)d_in[1];
    float* out        = (float*)d_out;

    const int BT = in_sizes[1] / 6;            // 64*28 = 1792
    const int n3 = in_sizes[0] / BT;           // 4096*3 = 12288 floats per bt

    const size_t wsNeed = (size_t)BT * 16 * sizeof(float);  // 114 KB
    if (d_ws != nullptr && ws_size >= wsNeed) {
        float* ws = (float*)d_ws;
        const int preBlocks = (BT + 255) / 256;
        se3_pre<<<dim3((unsigned)preBlocks), 256, 0, stream>>>(dofs, ws, BT);

        const int tilesPerBT = (n3 + 6143) / 6144;          // 2 for N=4096
        dim3 grid((unsigned)(BT * tilesPerBT));             // 3584 blocks
        se3_stream<<<grid, 256, 0, stream>>>(X, ws, out, n3, tilesPerBT);
    } else {
        const int tilesPerBT = (n3 + 3071) / 3072;
        dim3 grid((unsigned)(BT * tilesPerBT));
        se3_apply_fused<<<grid, 256, 0, stream>>>(X, dofs, out, n3, tilesPerBT);
    }
}

// Round 5
// 163.179 us; speedup vs baseline: 1.0259x; 1.0234x over previous
//
#include <hip/hip_runtime.h>

// SE(3) exp + point transform — round 5: HAND-SCHEDULED load pipeline.
//
// Discovery from R4 counters: VGPR_Count=20 while the source held 6 float4
// loads + 24 results "live" => hipcc serialized every round's intended
// prefetch into load->waitcnt->use chunks. R0/R1/R2/R4 all compiled to the
// same ~2-deep chunked stream — which is why they all measured 54-58 us.
// The MLP hypothesis was never actually tested.
//
// Fix (T4 pattern, rule 18): X loads are inline-asm global_load_dwordx4
// (invisible to compiler waitcnt logic); consumption gated by counted
// s_waitcnt vmcnt(3/6) + sched_barrier(0); stores counted in the budget;
// W fenced before the pipeline so the loop has zero compiler vector-mem ops.
// One block per (b,t), thread owns nIter=4 slots of 12 floats, depth-2 ring:
// steady state = 96 B/lane of reads continuously outstanding, vmcnt never
// drained to 0 inside the loop.

typedef float f4 __attribute__((ext_vector_type(4)));

// ---------------- kernel A: 1792x SE(3) exp -> ws (16 floats per bt) -------
__global__ __launch_bounds__(256) void se3_pre(
    const float* __restrict__ dofs, float* __restrict__ ws, int BT)
{
    const int i = blockIdx.x * 256 + threadIdx.x;
    if (i >= BT) return;
    const float* d = dofs + i * 6;
    const float tx = d[0], ty = d[1], tz = d[2];
    const float wx = d[3], wy = d[4], wz = d[5];

    const float nrm2  = wx * wx + wy * wy + wz * wz;
    const float th2   = fmaxf(nrm2, 1e-4f);      // jnp.clip(nrms, 1e-4)
    const float theta = sqrtf(th2);
    const float st = sinf(theta);
    const float ct = cosf(theta);
    const float f1 = st / theta;
    const float f2 = (1.0f - ct) / th2;
    const float f3 = (theta - st) / (th2 * theta);

    const float xx = wx * wx, yy = wy * wy, zz = wz * wz;
    const float xy = wx * wy, xz = wx * wz, yz = wy * wz;

    const float R00 = 1.0f - f2 * (yy + zz);
    const float R01 = f2 * xy - f1 * wz;
    const float R02 = f2 * xz + f1 * wy;
    const float R10 = f2 * xy + f1 * wz;
    const float R11 = 1.0f - f2 * (xx + zz);
    const float R12 = f2 * yz - f1 * wx;
    const float R20 = f2 * xz - f1 * wy;
    const float R21 = f2 * yz + f1 * wx;
    const float R22 = 1.0f - f2 * (xx + yy);

    const float V00 = 1.0f - f3 * (yy + zz);
    const float V01 = f3 * xy - f2 * wz;
    const float V02 = f3 * xz + f2 * wy;
    const float V10 = f3 * xy + f2 * wz;
    const float V11 = 1.0f - f3 * (xx + zz);
    const float V12 = f3 * yz - f2 * wx;
    const float V20 = f3 * xz - f2 * wy;
    const float V21 = f3 * yz + f2 * wx;
    const float V22 = 1.0f - f3 * (xx + yy);

    const float Tx = V00 * tx + V01 * ty + V02 * tz;
    const float Ty = V10 * tx + V11 * ty + V12 * tz;
    const float Tz = V20 * tx + V21 * ty + V22 * tz;

    f4* W = (f4*)(ws + (long long)i * 16);
    W[0] = (f4){R00, R01, R02, Tx};
    W[1] = (f4){R10, R11, R12, Ty};
    W[2] = (f4){R20, R21, R22, Tz};
}

// ---------------- kernel B: hand-pipelined streaming transform -------------
// One block per bt. slotsPerBT = n3/12 (multiple of 256 guaranteed by host).
// Thread handles slots t, t+256, ..., depth-2 asm-load ring.

#define PREF(b0, b1, b2, sIdx)                                                 \
    do {                                                                       \
        const f4* _p = (const f4*)(Xbt + (sIdx) * 12);                         \
        asm volatile("global_load_dwordx4 %0, %3, off\n\t"                     \
                     "global_load_dwordx4 %1, %3, off offset:16\n\t"           \
                     "global_load_dwordx4 %2, %3, off offset:32"               \
                     : "=&v"(b0), "=&v"(b1), "=&v"(b2)                         \
                     : "v"(_p)                                                 \
                     : "memory");                                              \
    } while (0)

#define CSTORE(b0, b1, b2, sIdx)                                               \
    do {                                                                       \
        const float x0 = b0.x, y0 = b0.y, z0 = b0.z;                           \
        const float x1 = b0.w, y1 = b1.x, z1 = b1.y;                           \
        const float x2 = b1.z, y2 = b1.w, z2 = b2.x;                           \
        const float x3 = b2.y, y3 = b2.z, z3 = b2.w;                           \
        f4 o0, o1, o2;                                                         \
        o0.x = fmaf(w0.x, x0, fmaf(w0.y, y0, fmaf(w0.z, z0, w0.w)));           \
        o0.y = fmaf(w1.x, x0, fmaf(w1.y, y0, fmaf(w1.z, z0, w1.w)));           \
        o0.z = fmaf(w2.x, x0, fmaf(w2.y, y0, fmaf(w2.z, z0, w2.w)));           \
        o0.w = fmaf(w0.x, x1, fmaf(w0.y, y1, fmaf(w0.z, z1, w0.w)));           \
        o1.x = fmaf(w1.x, x1, fmaf(w1.y, y1, fmaf(w1.z, z1, w1.w)));           \
        o1.y = fmaf(w2.x, x1, fmaf(w2.y, y1, fmaf(w2.z, z1, w2.w)));           \
        o1.z = fmaf(w0.x, x2, fmaf(w0.y, y2, fmaf(w0.z, z2, w0.w)));           \
        o1.w = fmaf(w1.x, x2, fmaf(w1.y, y2, fmaf(w1.z, z2, w1.w)));           \
        o2.x = fmaf(w2.x, x2, fmaf(w2.y, y2, fmaf(w2.z, z2, w2.w)));           \
        o2.y = fmaf(w0.x, x3, fmaf(w0.y, y3, fmaf(w0.z, z3, w0.w)));           \
        o2.z = fmaf(w1.x, x3, fmaf(w1.y, y3, fmaf(w1.z, z3, w1.w)));           \
        o2.w = fmaf(w2.x, x3, fmaf(w2.y, y3, fmaf(w2.z, z3, w2.w)));           \
        f4* _op = (f4*)(Obt + (sIdx) * 12);                                    \
        _op[0] = o0; _op[1] = o1; _op[2] = o2;                                 \
    } while (0)

__device__ __forceinline__ void waitv(int c) {
    // counted vmcnt gate; literal counts only. rule 18: sched_barrier after.
    if (c >= 6)      { asm volatile("s_waitcnt vmcnt(6)" ::: "memory"); }
    else if (c == 3) { asm volatile("s_waitcnt vmcnt(3)" ::: "memory"); }
    else             { asm volatile("s_waitcnt vmcnt(0)" ::: "memory"); }
    __builtin_amdgcn_sched_barrier(0);
}

__global__ __launch_bounds__(256) void se3_pipe(
    const float* __restrict__ X, const float* __restrict__ ws,
    float* __restrict__ out, int n3, int slotsPerBT)
{
    const int bt = blockIdx.x;
    const int t  = threadIdx.x;
    const float* __restrict__ Xbt = X   + (long long)bt * n3;
    float*       __restrict__ Obt = out + (long long)bt * n3;

    // ---- W once per thread; force-materialize + drain so vmcnt baseline = 0
    const f4* Wp = (const f4*)(ws + (long long)bt * 16);
    const f4 w0 = Wp[0], w1 = Wp[1], w2 = Wp[2];
    asm volatile("" :: "v"(w0), "v"(w1), "v"(w2));            // issue + wait now
    asm volatile("s_waitcnt vmcnt(0) lgkmcnt(0)" ::: "memory");
    __builtin_amdgcn_sched_barrier(0);

    const int nIter = slotsPerBT >> 8;   // slots per thread (4 for N=4096)

    f4 A0, A1, A2, B0, B1, B2;
    // ---- prologue: put slots s0, s1 in flight ----
    PREF(A0, A1, A2, t);
    if (nIter > 1) PREF(B0, B1, B2, t + 256);

    // Issue order (FIFO): L0 L1 [S0 L2] [S1 L3] [S2 L4] ... waits:
    //   step i consumes L_i; ops issued after L_i at the wait point =
    //   3*(i>=1 stores) + 3*(L_{i+1} exists) -> 3,6,6,...,6,3.
    int i = 0;
    while (i < nIter) {
        {   // ring slot A, slot index s = t + 256*i
            waitv(3 * (i >= 1) + 3 * ((i + 1) < nIter));
            CSTORE(A0, A1, A2, t + 256 * i);
            if (i + 2 < nIter) PREF(A0, A1, A2, t + 256 * (i + 2));
            ++i;
        }
        if (i < nIter) {   // ring slot B
            waitv(3 + 3 * ((i + 1) < nIter));
            CSTORE(B0, B1, B2, t + 256 * i);
            if (i + 2 < nIter) PREF(B0, B1, B2, t + 256 * (i + 2));
            ++i;
        }
    }
}

// ---------------- fallback (R1 structure) for non-conforming shapes --------
__device__ __forceinline__ float rfl(float x) {
    return __uint_as_float(__builtin_amdgcn_readfirstlane(__float_as_uint(x)));
}

__global__ __launch_bounds__(256) void se3_apply_fused(
    const float* __restrict__ X, const float* __restrict__ dofs,
    float* __restrict__ out, int n3, int tilesPerBT)
{
    const int bt   = blockIdx.x / tilesPerBT;
    const int tile = blockIdx.x - bt * tilesPerBT;
    const int t    = threadIdx.x;
    const int fInBT = tile * 3072 + t * 12;
    const long long baseF = (long long)bt * (long long)n3 + (long long)fInBT;
    const f4* __restrict__ Xp = (const f4*)(X + baseF);
    f4* __restrict__ Op       = (f4*)(out + baseF);

    const bool full = (fInBT + 12) <= n3;
    f4 v0, v1, v2;
    if (full) { v0 = Xp[0]; v1 = Xp[1]; v2 = Xp[2]; }

    const float* d = dofs + bt * 6;
    const float tx = d[0], ty = d[1], tz = d[2];
    const float wx = d[3], wy = d[4], wz = d[5];
    const float nrm2  = wx * wx + wy * wy + wz * wz;
    const float th2   = fmaxf(nrm2, 1e-4f);
    const float theta = sqrtf(th2);
    const float st = sinf(theta), ct = cosf(theta);
    const float f1 = st / theta;
    const float f2 = (1.0f - ct) / th2;
    const float f3 = (theta - st) / (th2 * theta);
    const float xx = wx * wx, yy = wy * wy, zz = wz * wz;
    const float xy = wx * wy, xz = wx * wz, yz = wy * wz;
    const float R00 = rfl(1.0f - f2 * (yy + zz));
    const float R01 = rfl(f2 * xy - f1 * wz);
    const float R02 = rfl(f2 * xz + f1 * wy);
    const float R10 = rfl(f2 * xy + f1 * wz);
    const float R11 = rfl(1.0f - f2 * (xx + zz));
    const float R12 = rfl(f2 * yz - f1 * wx);
    const float R20 = rfl(f2 * xz - f1 * wy);
    const float R21 = rfl(f2 * yz + f1 * wx);
    const float R22 = rfl(1.0f - f2 * (xx + yy));
    const float V00 = 1.0f - f3 * (yy + zz);
    const float V01 = f3 * xy - f2 * wz;
    const float V02 = f3 * xz + f2 * wy;
    const float V10 = f3 * xy + f2 * wz;
    const float V11 = 1.0f - f3 * (xx + zz);
    const float V12 = f3 * yz - f2 * wx;
    const float V20 = f3 * xz - f2 * wy;
    const float V21 = f3 * yz + f2 * wx;
    const float V22 = 1.0f - f3 * (xx + yy);
    const float Tx = rfl(V00 * tx + V01 * ty + V02 * tz);
    const float Ty = rfl(V10 * tx + V11 * ty + V12 * tz);
    const float Tz = rfl(V20 * tx + V21 * ty + V22 * tz);

    if (full) {
        const float x0 = v0.x, y0 = v0.y, z0 = v0.z;
        const float x1 = v0.w, y1 = v1.x, z1 = v1.y;
        const float x2 = v1.z, y2 = v1.w, z2 = v2.x;
        const float x3 = v2.y, y3 = v2.z, z3 = v2.w;
        f4 o0, o1, o2;
        o0.x = fmaf(R00, x0, fmaf(R01, y0, fmaf(R02, z0, Tx)));
        o0.y = fmaf(R10, x0, fmaf(R11, y0, fmaf(R12, z0, Ty)));
        o0.z = fmaf(R20, x0, fmaf(R21, y0, fmaf(R22, z0, Tz)));
        o0.w = fmaf(R00, x1, fmaf(R01, y1, fmaf(R02, z1, Tx)));
        o1.x = fmaf(R10, x1, fmaf(R11, y1, fmaf(R12, z1, Ty)));
        o1.y = fmaf(R20, x1, fmaf(R21, y1, fmaf(R22, z1, Tz)));
        o1.z = fmaf(R00, x2, fmaf(R01, y2, fmaf(R02, z2, Tx)));
        o1.w = fmaf(R10, x2, fmaf(R11, y2, fmaf(R12, z2, Ty)));
        o2.x = fmaf(R20, x2, fmaf(R21, y2, fmaf(R22, z2, Tz)));
        o2.y = fmaf(R00, x3, fmaf(R01, y3, fmaf(R02, z3, Tx)));
        o2.z = fmaf(R10, x3, fmaf(R11, y3, fmaf(R12, z3, Ty)));
        o2.w = fmaf(R20, x3, fmaf(R21, y3, fmaf(R22, z3, Tz)));
        Op[0] = o0; Op[1] = o1; Op[2] = o2;
    } else {
        const long long base = (long long)bt * (long long)n3;
        for (int f = fInBT; f + 3 <= n3 && f < fInBT + 12; f += 3) {
            const float px = X[base + f + 0], py = X[base + f + 1], pz = X[base + f + 2];
            out[base + f + 0] = fmaf(R00, px, fmaf(R01, py, fmaf(R02, pz, Tx)));
            out[base + f + 1] = fmaf(R10, px, fmaf(R11, py, fmaf(R12, pz, Ty)));
            out[base + f + 2] = fmaf(R20, px, fmaf(R21, py, fmaf(R22, pz, Tz)));
        }
    }
}

extern "C" void kernel_launch(void* const* d_in, const int* in_sizes, int n_in,
                              void* d_out, int out_size, void* d_ws, size_t ws_size,
                              hipStream_t stream) {
    const float* X    = (const float*)d_in[0];
    const float* dofs = (const float*)d_in[1];
    float* out        = (float*)d_out;

    const int BT = in_sizes[1] / 6;            // 64*28 = 1792
    const int n3 = in_sizes[0] / BT;           // 4096*3 = 12288 floats per bt

    const size_t wsNeed = (size_t)BT * 16 * sizeof(float);  // 114 KB
    // pipelined path requires: slots of 12 floats, whole slots per thread
    // (n3 % 3072 == 0 -> slotsPerBT % 256 == 0), and workspace for W.
    if (d_ws != nullptr && ws_size >= wsNeed && (n3 % 3072) == 0) {
        float* ws = (float*)d_ws;
        const int preBlocks = (BT + 255) / 256;
        se3_pre<<<dim3((unsigned)preBlocks), 256, 0, stream>>>(dofs, ws, BT);

        const int slotsPerBT = n3 / 12;                     // 1024 for N=4096
        se3_pipe<<<dim3((unsigned)BT), 256, 0, stream>>>(X, ws, out, n3, slotsPerBT);
    } else {
        const int tilesPerBT = (n3 + 3071) / 3072;
        dim3 grid((unsigned)(BT * tilesPerBT));
        se3_apply_fused<<<grid, 256, 0, stream>>>(X, dofs, out, n3, tilesPerBT);
    }
}

// Round 6
// 159.053 us; speedup vs baseline: 1.0525x; 1.0259x over previous
//
#include <hip/hip_runtime.h>

// SE(3) exp + point transform — round 6: whole-point (dwordx3) streaming,
// the copy-identical discriminator.
//
// Ledger: R0 LDS-coalesced / R1 48B-stride regs / R2 persistent+amortized
// SE3 / R3 nt stores / R4 copy-shaped 96B / R5 hand-scheduled 6-deep vmcnt
// pipeline — ALL ~54 us at 2.4-2.6 TB/s fabric. R3 marginal-byte analysis:
// +28 MB fabric -> +11 us => 2.5 TB/s marginal service rate. The one
// combination never tested (and the m13-copy shape): near-contiguous lane
// addressing WITHOUT LDS/barriers. Here each lane owns one point: 12 B at
// base+12*lane -> each wave load covers 12 fully-consumed 64B lines (copy-
// grade coverage), zero repacking. W per (b,t) from the pre-kernel via the
// uniform/scalar path. If this is still ~54 us, the 2.5 TB/s cap is benched
// platform behavior for this size/mix -> roofline.

typedef float f4 __attribute__((ext_vector_type(4)));

struct F3 { float x, y, z; };   // 12 B, 4-B aligned -> dwordx3

// ---------------- kernel A: 1792x SE(3) exp -> ws (16 floats per bt) -------
__global__ __launch_bounds__(256) void se3_pre(
    const float* __restrict__ dofs, float* __restrict__ ws, int BT)
{
    const int i = blockIdx.x * 256 + threadIdx.x;
    if (i >= BT) return;
    const float* d = dofs + i * 6;
    const float tx = d[0], ty = d[1], tz = d[2];
    const float wx = d[3], wy = d[4], wz = d[5];

    const float nrm2  = wx * wx + wy * wy + wz * wz;
    const float th2   = fmaxf(nrm2, 1e-4f);      // jnp.clip(nrms, 1e-4)
    const float theta = sqrtf(th2);
    const float st = sinf(theta);
    const float ct = cosf(theta);
    const float f1 = st / theta;
    const float f2 = (1.0f - ct) / th2;
    const float f3 = (theta - st) / (th2 * theta);

    const float xx = wx * wx, yy = wy * wy, zz = wz * wz;
    const float xy = wx * wy, xz = wx * wz, yz = wy * wz;

    const float R00 = 1.0f - f2 * (yy + zz);
    const float R01 = f2 * xy - f1 * wz;
    const float R02 = f2 * xz + f1 * wy;
    const float R10 = f2 * xy + f1 * wz;
    const float R11 = 1.0f - f2 * (xx + zz);
    const float R12 = f2 * yz - f1 * wx;
    const float R20 = f2 * xz - f1 * wy;
    const float R21 = f2 * yz + f1 * wx;
    const float R22 = 1.0f - f2 * (xx + yy);

    const float V00 = 1.0f - f3 * (yy + zz);
    const float V01 = f3 * xy - f2 * wz;
    const float V02 = f3 * xz + f2 * wy;
    const float V10 = f3 * xy + f2 * wz;
    const float V11 = 1.0f - f3 * (xx + zz);
    const float V12 = f3 * yz - f2 * wx;
    const float V20 = f3 * xz - f2 * wy;
    const float V21 = f3 * yz + f2 * wx;
    const float V22 = 1.0f - f3 * (xx + yy);

    const float Tx = V00 * tx + V01 * ty + V02 * tz;
    const float Ty = V10 * tx + V11 * ty + V12 * tz;
    const float Tz = V20 * tx + V21 * ty + V22 * tz;

    f4* W = (f4*)(ws + (long long)i * 16);
    W[0] = (f4){R00, R01, R02, Tx};
    W[1] = (f4){R10, R11, R12, Ty};
    W[2] = (f4){R20, R21, R22, Tz};
}

// ---------------- kernel B: whole-point dwordx3 stream ---------------------
// tile = 1024 points; thread owns points t+256k, k=0..3 (copy-grade lane
// contiguity: 12 B/lane, each wave-instr covers 12 full cache lines).
__global__ __launch_bounds__(256) void se3_pts(
    const float* __restrict__ X, const float* __restrict__ ws,
    float* __restrict__ out, int nPts, int tilesPerBT)
{
    const int bt   = blockIdx.x / tilesPerBT;
    const int tile = blockIdx.x - bt * tilesPerBT;
    const int t    = threadIdx.x;

    const long long basePt = (long long)bt * (long long)nPts + (long long)tile * 1024;
    const F3* __restrict__ Xp = (const F3*)X + basePt;
    F3*       __restrict__ Op = (F3*)out + basePt;

    // W per (b,t): block-uniform address -> scalar loads, no vmem traffic
    const f4* Wp = (const f4*)(ws + (long long)bt * 16);
    const f4 w0 = Wp[0], w1 = Wp[1], w2 = Wp[2];

    const int lim = nPts - tile * 1024;   // points remaining in this tile

    // issue all loads first (compiler-natural; R5 proved depth is not binding)
    F3 v[4];
    bool g[4];
#pragma unroll
    for (int k = 0; k < 4; ++k) {
        g[k] = (t + 256 * k) < lim;
        if (g[k]) v[k] = Xp[t + 256 * k];
    }
#pragma unroll
    for (int k = 0; k < 4; ++k) {
        if (g[k]) {
            const float x = v[k].x, y = v[k].y, z = v[k].z;
            F3 o;
            o.x = fmaf(w0.x, x, fmaf(w0.y, y, fmaf(w0.z, z, w0.w)));
            o.y = fmaf(w1.x, x, fmaf(w1.y, y, fmaf(w1.z, z, w1.w)));
            o.z = fmaf(w2.x, x, fmaf(w2.y, y, fmaf(w2.z, z, w2.w)));
            Op[t + 256 * k] = o;
        }
    }
}

// ---------------- fallback (R1 structure) if no workspace ------------------
__device__ __forceinline__ float rfl(float x) {
    return __uint_as_float(__builtin_amdgcn_readfirstlane(__float_as_uint(x)));
}

__global__ __launch_bounds__(256) void se3_apply_fused(
    const float* __restrict__ X, const float* __restrict__ dofs,
    float* __restrict__ out, int n3, int tilesPerBT)
{
    const int bt   = blockIdx.x / tilesPerBT;
    const int tile = blockIdx.x - bt * tilesPerBT;
    const int t    = threadIdx.x;
    const int fInBT = tile * 3072 + t * 12;
    const long long baseF = (long long)bt * (long long)n3 + (long long)fInBT;
    const f4* __restrict__ Xp = (const f4*)(X + baseF);
    f4* __restrict__ Op       = (f4*)(out + baseF);

    const bool full = (fInBT + 12) <= n3;
    f4 v0, v1, v2;
    if (full) { v0 = Xp[0]; v1 = Xp[1]; v2 = Xp[2]; }

    const float* d = dofs + bt * 6;
    const float tx = d[0], ty = d[1], tz = d[2];
    const float wx = d[3], wy = d[4], wz = d[5];
    const float nrm2  = wx * wx + wy * wy + wz * wz;
    const float th2   = fmaxf(nrm2, 1e-4f);
    const float theta = sqrtf(th2);
    const float st = sinf(theta), ct = cosf(theta);
    const float f1 = st / theta;
    const float f2 = (1.0f - ct) / th2;
    const float f3 = (theta - st) / (th2 * theta);
    const float xx = wx * wx, yy = wy * wy, zz = wz * wz;
    const float xy = wx * wy, xz = wx * wz, yz = wy * wz;
    const float R00 = rfl(1.0f - f2 * (yy + zz));
    const float R01 = rfl(f2 * xy - f1 * wz);
    const float R02 = rfl(f2 * xz + f1 * wy);
    const float R10 = rfl(f2 * xy + f1 * wz);
    const float R11 = rfl(1.0f - f2 * (xx + zz));
    const float R12 = rfl(f2 * yz - f1 * wx);
    const float R20 = rfl(f2 * xz - f1 * wy);
    const float R21 = rfl(f2 * yz + f1 * wx);
    const float R22 = rfl(1.0f - f2 * (xx + yy));
    const float V00 = 1.0f - f3 * (yy + zz);
    const float V01 = f3 * xy - f2 * wz;
    const float V02 = f3 * xz + f2 * wy;
    const float V10 = f3 * xy + f2 * wz;
    const float V11 = 1.0f - f3 * (xx + zz);
    const float V12 = f3 * yz - f2 * wx;
    const float V20 = f3 * xz - f2 * wy;
    const float V21 = f3 * yz + f2 * wx;
    const float V22 = 1.0f - f3 * (xx + yy);
    const float Tx = rfl(V00 * tx + V01 * ty + V02 * tz);
    const float Ty = rfl(V10 * tx + V11 * ty + V12 * tz);
    const float Tz = rfl(V20 * tx + V21 * ty + V22 * tz);

    if (full) {
        const float x0 = v0.x, y0 = v0.y, z0 = v0.z;
        const float x1 = v0.w, y1 = v1.x, z1 = v1.y;
        const float x2 = v1.z, y2 = v1.w, z2 = v2.x;
        const float x3 = v2.y, y3 = v2.z, z3 = v2.w;
        f4 o0, o1, o2;
        o0.x = fmaf(R00, x0, fmaf(R01, y0, fmaf(R02, z0, Tx)));
        o0.y = fmaf(R10, x0, fmaf(R11, y0, fmaf(R12, z0, Ty)));
        o0.z = fmaf(R20, x0, fmaf(R21, y0, fmaf(R22, z0, Tz)));
        o0.w = fmaf(R00, x1, fmaf(R01, y1, fmaf(R02, z1, Tx)));
        o1.x = fmaf(R10, x1, fmaf(R11, y1, fmaf(R12, z1, Ty)));
        o1.y = fmaf(R20, x1, fmaf(R21, y1, fmaf(R22, z1, Tz)));
        o1.z = fmaf(R00, x2, fmaf(R01, y2, fmaf(R02, z2, Tx)));
        o1.w = fmaf(R10, x2, fmaf(R11, y2, fmaf(R12, z2, Ty)));
        o2.x = fmaf(R20, x2, fmaf(R21, y2, fmaf(R22, z2, Tz)));
        o2.y = fmaf(R00, x3, fmaf(R01, y3, fmaf(R02, z3, Tx)));
        o2.z = fmaf(R10, x3, fmaf(R11, y3, fmaf(R12, z3, Ty)));
        o2.w = fmaf(R20, x3, fmaf(R21, y3, fmaf(R22, z3, Tz)));
        Op[0] = o0; Op[1] = o1; Op[2] = o2;
    } else {
        const long long base = (long long)bt * (long long)n3;
        for (int f = fInBT; f + 3 <= n3 && f < fInBT + 12; f += 3) {
            const float px = X[base + f + 0], py = X[base + f + 1], pz = X[base + f + 2];
            out[base + f + 0] = fmaf(R00, px, fmaf(R01, py, fmaf(R02, pz, Tx)));
            out[base + f + 1] = fmaf(R10, px, fmaf(R11, py, fmaf(R12, pz, Ty)));
            out[base + f + 2] = fmaf(R20, px, fmaf(R21, py, fmaf(R22, pz, Tz)));
        }
    }
}

extern "C" void kernel_launch(void* const* d_in, const int* in_sizes, int n_in,
                              void* d_out, int out_size, void* d_ws, size_t ws_size,
                              hipStream_t stream) {
    const float* X    = (const float*)d_in[0];
    const float* dofs = (const float*)d_in[1];
    float* out        = (float*)d_out;

    const int BT = in_sizes[1] / 6;            // 64*28 = 1792
    const int n3 = in_sizes[0] / BT;           // 4096*3 = 12288 floats per bt

    const size_t wsNeed = (size_t)BT * 16 * sizeof(float);  // 114 KB
    if (d_ws != nullptr && ws_size >= wsNeed && (n3 % 3) == 0) {
        float* ws = (float*)d_ws;
        const int preBlocks = (BT + 255) / 256;
        se3_pre<<<dim3((unsigned)preBlocks), 256, 0, stream>>>(dofs, ws, BT);

        const int nPts = n3 / 3;                            // 4096
        const int tilesPerBT = (nPts + 1023) / 1024;        // 4
        dim3 grid((unsigned)(BT * tilesPerBT));             // 7168 blocks
        se3_pts<<<grid, 256, 0, stream>>>(X, ws, out, nPts, tilesPerBT);
    } else {
        const int tilesPerBT = (n3 + 3071) / 3072;
        dim3 grid((unsigned)(BT * tilesPerBT));
        se3_apply_fused<<<grid, 256, 0, stream>>>(X, dofs, out, n3, tilesPerBT);
    }
}